// Round 8
// baseline (163.723 us; speedup 1.0000x reference)
//
#include <hip/hip_runtime.h>

typedef unsigned short u16;
typedef __bf16   bf16x8 __attribute__((ext_vector_type(8)));
typedef float    f32x4  __attribute__((ext_vector_type(4)));
typedef float    f32x16 __attribute__((ext_vector_type(16)));
typedef unsigned u32x4v __attribute__((ext_vector_type(4)));
typedef u16      u16x8  __attribute__((ext_vector_type(8)));

#define DEV __device__ __forceinline__

DEV u16 tobf(float f) {               // RNE via HW convert
  return __builtin_bit_cast(unsigned short, (__bf16)f);
}

DEV unsigned pack2(float a, float b) { // 2xf32 -> packed 2xbf16
  return (unsigned)tobf(a) | ((unsigned)tobf(b) << 16);
}

DEV f32x4 fzero() { f32x4 z; z[0]=0.f; z[1]=0.f; z[2]=0.f; z[3]=0.f; return z; }

DEV void async_cp16(void* lds, const void* g) {
  __builtin_amdgcn_global_load_lds(
      (const __attribute__((address_space(1))) void*)g,
      (__attribute__((address_space(3))) void*)lds, 16, 0, 0);
}

DEV void cvt8(const float* __restrict__ in, u16* __restrict__ out, int i) {
  const float4* in4 = (const float4*)in;
  float4 a = in4[2*i], b = in4[2*i+1];
  u16x8 r;
  r[0]=tobf(a.x); r[1]=tobf(a.y); r[2]=tobf(a.z); r[3]=tobf(a.w);
  r[4]=tobf(b.x); r[5]=tobf(b.y); r[6]=tobf(b.z); r[7]=tobf(b.w);
  *(u16x8*)(out + 8*(size_t)i) = r;
}

// ---------------- fused pre-pass: f32->bf16 converts + mask-nonzero OR -------
__global__ __launch_bounds__(256)
void k_pre(const float* __restrict__ x, const float* __restrict__ wqkv,
           const float* __restrict__ wproj,
           u16* __restrict__ xb, u16* __restrict__ wqkvb, u16* __restrict__ wprojb,
           const u32x4v* __restrict__ mask, unsigned* __restrict__ flag)
{
  const int tid = blockIdx.x * blockDim.x + threadIdx.x;
  const int stride = gridDim.x * blockDim.x;
  for (int i = tid; i < 524288; i += stride) cvt8(x, xb, i);
  for (int i = tid; i < 393216; i += stride) cvt8(wqkv, wqkvb, i);
  for (int i = tid; i < 131072; i += stride) cvt8(wproj, wprojb, i);
  unsigned o = 0;
  for (int i = tid; i < 2097152; i += stride) {
    u32x4v v = mask[i];
    o |= v[0] | v[1] | v[2] | v[3];
  }
  if (o & 0x7fffffffu) atomicOr(flag, 1u);         // ignore -0.0
}

// ---------------- NT GEMM: C[m,n] = sum_k A[m,k]*B[n,k], bf16 in, f32 acc ----
template<int EPI>
__global__ __launch_bounds__(256)
void k_gemm_nt(const u16* __restrict__ A, const u16* __restrict__ B,
               int N, int K, int nbn,
               const float* __restrict__ bq, const float* __restrict__ bk,
               const float* __restrict__ bv,
               u16* __restrict__ qo, u16* __restrict__ ko, u16* __restrict__ vto,
               float* __restrict__ fo, const float* __restrict__ bp)
{
  __shared__ u16 sA[2][4096];   // [128][32] bf16, chunk-swizzled
  __shared__ u16 sB[2][4096];

  const int tid  = threadIdx.x;
  const int lane = tid & 63;
  const int wave = tid >> 6;
  const int lr = lane & 15, lg = lane >> 4;
  const int wr = wave >> 1, wc = wave & 1;

  const int per = gridDim.x >> 3;
  const int bid = blockIdx.x;
  const int swz = (bid & 7) * per + (bid >> 3);
  const int bm0 = (swz / nbn) << 7;
  const int bn0 = (swz - (swz / nbn) * nbn) << 7;

  const size_t Kb = (size_t)K * 2;

  auto stage = [&](int buf, int kt) {
#pragma unroll
    for (int j = 0; j < 2; ++j) {
      int off = (tid + j * 256) << 4;
      int row = off >> 6;
      int ch  = (off & 63) >> 4;
      int gch = ch ^ (row & 3);
      async_cp16((char*)&sA[buf][0] + off,
                 (const char*)A + (size_t)(bm0 + row) * Kb + (size_t)kt * 64 + gch * 16);
      async_cp16((char*)&sB[buf][0] + off,
                 (const char*)B + (size_t)(bn0 + row) * Kb + (size_t)kt * 64 + gch * 16);
    }
  };

  f32x4 acc[4][4];
#pragma unroll
  for (int i = 0; i < 4; ++i)
#pragma unroll
    for (int j = 0; j < 4; ++j) acc[i][j] = fzero();

  const int nk = K >> 5;
  stage(0, 0);
  __syncthreads();

  for (int kt = 0; kt < nk; ++kt) {
    const int cur = kt & 1;
    if (kt + 1 < nk) stage(cur ^ 1, kt + 1);

    bf16x8 af[4], bfr[4];
#pragma unroll
    for (int mi = 0; mi < 4; ++mi) {
      int row = (wr << 6) + (mi << 4) + lr;
      int addr = (row << 6) + ((lg ^ (row & 3)) << 4);
      af[mi] = *(const bf16x8*)((const char*)&sA[cur][0] + addr);
    }
#pragma unroll
    for (int ni = 0; ni < 4; ++ni) {
      int row = (wc << 6) + (ni << 4) + lr;
      int addr = (row << 6) + ((lg ^ (row & 3)) << 4);
      bfr[ni] = *(const bf16x8*)((const char*)&sB[cur][0] + addr);
    }
#pragma unroll
    for (int mi = 0; mi < 4; ++mi)
#pragma unroll
      for (int ni = 0; ni < 4; ++ni)
        acc[mi][ni] = __builtin_amdgcn_mfma_f32_16x16x32_bf16(af[mi], bfr[ni], acc[mi][ni], 0, 0, 0);

    __syncthreads();
  }

#pragma unroll
  for (int mi = 0; mi < 4; ++mi) {
#pragma unroll
    for (int ni = 0; ni < 4; ++ni) {
      int col = bn0 + (wc << 6) + (ni << 4) + lr;
      if (EPI == 0) {
        int s = col >> 10, hd = col & 1023;
        int h = hd >> 6, d = hd & 63;
        float bias = (s == 0 ? bq[hd] : (s == 1 ? bk[hd] : bv[hd]));
#pragma unroll
        for (int r = 0; r < 4; ++r) {
          int m = bm0 + (wr << 6) + (mi << 4) + (lg << 2) + r;
          int b = m >> 11, n = m & 2047;
          float v = acc[mi][ni][r] + bias;
          if (s == 0) v *= 0.125f;            // fold hd^-0.5 into Q (exact pow2)
          u16 val = tobf(v);
          size_t bh = (size_t)(b * 16 + h);
          if (s == 0)      qo[(bh * 2048 + n) * 64 + d] = val;
          else if (s == 1) ko[(bh * 2048 + n) * 64 + d] = val;
          else             vto[(bh * 64 + d) * 2048 + n] = val;  // V transposed
        }
      } else {
        float bias = bp[col];
#pragma unroll
        for (int r = 0; r < 4; ++r) {
          int m = bm0 + (wr << 6) + (mi << 4) + (lg << 2) + r;
          fo[(size_t)m * N + col] = acc[mi][ni][r] + bias;
        }
      }
    }
  }
}

// ---------------- flash attention: 1-wave blocks, ZERO barriers --------------
// grid = B*H*(N/32) = 2048 blocks x 64 threads. Each wave owns 32 q-rows and
// privately stages its KV tiles (32 keys) into its own double-buffered LDS via
// global_load_lds. No __syncthreads anywhere: correctness = counted vmcnt(8)
// (next tile's 8 loads stay in flight; prior tile's are drained) + rule-18
// sched_barrier. Swapped QK^T (mfma(K,Q)) -> lane owns q = lane&31; P ->
// A-frag via v_permlane32_swap_b32. Q pre-scaled by 0.125 at QKV epilogue.
__global__ __launch_bounds__(64)
void k_attn(const u16* __restrict__ qb, const u16* __restrict__ kb,
            const u16* __restrict__ vtb, u16* __restrict__ ao,
            const float* __restrict__ mask, const unsigned* __restrict__ flag)
{
  constexpr int N = 2048;
  constexpr int NT = N / 32;       // 64 KV tiles of 32 keys
  __shared__ u16 sK[2][2048];      // [32 keys][64 d] bf16, 128B rows, chunk-swz
  __shared__ u16 sV[2][2048];      // [64 d][32 keys] (V^T), 64B rows, chunk-swz

  const int lane = threadIdx.x & 63;
  const int l31  = lane & 31;
  const int hi   = lane >> 5;

  const int bid  = blockIdx.x;
  const int xcd  = bid & 7, slot = bid >> 3;   // slot 0..255 per XCD
  const int qt   = slot >> 2;                  // 0..63
  const int bh   = xcd + 8 * (slot & 3);       // 4 heads per XCD -> 2MB L2-resident
  const int b    = bh >> 4, h = bh & 15;

  const char* Kb8 = (const char*)(kb  + (size_t)bh * N * 64);
  const char* Vb8 = (const char*)(vtb + (size_t)bh * 64 * N);
  const int q_lo = qt * 32;
  const int qg   = q_lo + l31;

  // Q B-frag: lane holds Q[q=l31][d = ks*16 + hi*8 + j]  (pre-scaled by 0.125)
  bf16x8 qf[4];
  {
    const u16* qrow = qb + ((size_t)bh * N + qg) * 64;
#pragma unroll
    for (int ks = 0; ks < 4; ++ks)
      qf[ks] = *(const bf16x8*)(qrow + ks * 16 + hi * 8);
  }

  const unsigned use_mask = *flag;
  const float* maskb = mask + (size_t)b * N * N;

  float m_run = -INFINITY, lsum = 0.f;
  f32x16 o0, o1;
#pragma unroll
  for (int r = 0; r < 16; ++r) { o0[r] = 0.f; o1[r] = 0.f; }

  // 8 loads per tile: 4 for K (4KB, 128B rows), 4 for V^T (4KB, 64B rows)
  auto stage = [&](int buf, int kt) {
#pragma unroll
    for (int j = 0; j < 4; ++j) {
      int off = (lane + j * 64) << 4;
      int row = off >> 7;                       // 0..31
      int ch  = (off & 127) >> 4;               // 0..7
      int gch = ch ^ (row & 7);
      async_cp16((char*)&sK[buf][0] + off,
                 Kb8 + (size_t)(kt * 32 + row) * 128 + gch * 16);
    }
#pragma unroll
    for (int j = 0; j < 4; ++j) {
      int off = (lane + j * 64) << 4;
      int row = off >> 6;                       // 0..63 (d)
      int ch  = (off & 63) >> 4;                // 0..3
      int gch = ch ^ ((row >> 1) & 3);
      async_cp16((char*)&sV[buf][0] + off,
                 Vb8 + (size_t)row * (N * 2) + kt * 64 + gch * 16);
    }
  };

  stage(0, 0);

  const float L2E = 1.44269504088896340736f;

  for (int t = 0; t < NT; ++t) {
    const int cur = t & 1;
    if (t + 1 < NT) {
      stage(cur ^ 1, t + 1);                    // issue next tile first (T14)
      asm volatile("s_waitcnt vmcnt(8)" ::: "memory");   // counted: tile t done
    } else {
      asm volatile("s_waitcnt vmcnt(0)" ::: "memory");
    }
    __builtin_amdgcn_sched_barrier(0);          // rule #18: pin ds_reads below

    const char* kbase = (const char*)&sK[cur][0];
    const char* vbase = (const char*)&sV[cur][0];

    // S^T[key][q=l31]: 4 d-slices of 16
    f32x16 sc;
#pragma unroll
    for (int r = 0; r < 16; ++r) sc[r] = 0.f;
    __builtin_amdgcn_s_setprio(1);
#pragma unroll
    for (int ks = 0; ks < 4; ++ks) {
      int a0 = (l31 << 7) + ((((ks << 1) + hi) ^ (l31 & 7)) << 4);
      bf16x8 kf = *(const bf16x8*)(kbase + a0);
      sc = __builtin_amdgcn_mfma_f32_32x32x16_bf16(kf, qf[ks], sc, 0, 0, 0);
    }
    __builtin_amdgcn_s_setprio(0);

    if (use_mask) {                      // slow path only if mask != 0
#pragma unroll
      for (int r = 0; r < 16; ++r) {
        int krow = (r & 3) + 8 * (r >> 2) + 4 * hi;
        sc[r] += maskb[(size_t)qg * N + t * 32 + krow];
      }
    }

    // row max over 32 keys: in-lane tree (16 vals) + xor32
    float tm[8];
#pragma unroll
    for (int r = 0; r < 8; ++r) tm[r] = fmaxf(sc[r], sc[r + 8]);
#pragma unroll
    for (int r = 0; r < 4; ++r) tm[r] = fmaxf(tm[r], tm[r + 4]);
    float pm = fmaxf(fmaxf(tm[0], tm[1]), fmaxf(tm[2], tm[3]));
    pm = fmaxf(pm, __shfl_xor(pm, 32, 64));

    // defer-max (T13): rescale only when running max grows past THR=8
    if (__any(pm > m_run + 8.f)) {
      const float m_new = fmaxf(m_run, pm);
      const float f = __builtin_amdgcn_exp2f((m_run - m_new) * L2E);
      m_run = m_new;
#pragma unroll
      for (int r = 0; r < 16; ++r) {
        float fr = __shfl(f, (r & 3) + 8 * (r >> 2) + 4 * hi, 64);
        o0[r] *= fr; o1[r] *= fr;
      }
      lsum *= f;
    }

    // p = exp(s - m); 4-way partial sums
    const float mL2 = m_run * L2E;
    float rs0 = 0.f, rs1 = 0.f, rs2 = 0.f, rs3 = 0.f;
#pragma unroll
    for (int r = 0; r < 16; r += 4) {
      sc[r]   = __builtin_amdgcn_exp2f(__builtin_fmaf(sc[r],   L2E, -mL2));
      sc[r+1] = __builtin_amdgcn_exp2f(__builtin_fmaf(sc[r+1], L2E, -mL2));
      sc[r+2] = __builtin_amdgcn_exp2f(__builtin_fmaf(sc[r+2], L2E, -mL2));
      sc[r+3] = __builtin_amdgcn_exp2f(__builtin_fmaf(sc[r+3], L2E, -mL2));
      rs0 += sc[r]; rs1 += sc[r+1]; rs2 += sc[r+2]; rs3 += sc[r+3];
    }
    float rs = (rs0 + rs1) + (rs2 + rs3);
    rs += __shfl_xor(rs, 32, 64);
    lsum += rs;

    // pack pairs -> P32[8]
    unsigned P32[8];
#pragma unroll
    for (int tt = 0; tt < 8; ++tt)
      P32[tt] = pack2(sc[2 * tt], sc[2 * tt + 1]);

    // redistribute to PV A-frag via permlane32_swap
    bf16x8 pa[2];
#pragma unroll
    for (int ks16 = 0; ks16 < 2; ++ks16) {
      const int b4 = ks16 << 2;
      unsigned c0 = P32[b4], c2 = P32[b4 + 2], c1 = P32[b4 + 1], c3 = P32[b4 + 3];
      asm volatile("v_permlane32_swap_b32 %0, %1" : "+v"(c0), "+v"(c2));
      asm volatile("v_permlane32_swap_b32 %0, %1" : "+v"(c1), "+v"(c3));
      u32x4v w; w[0] = c0; w[1] = c1; w[2] = c2; w[3] = c3;
      pa[ks16] = __builtin_bit_cast(bf16x8, w);
    }

    // O += P * V : B-frag from V^T rows (d = l31 / 32+l31), 2 key-slices
    __builtin_amdgcn_s_setprio(1);
#pragma unroll
    for (int ks16 = 0; ks16 < 2; ++ks16) {
      int a0 = (l31 << 6) + ((((ks16 << 1) + hi) ^ ((l31 >> 1) & 3)) << 4);
      bf16x8 vf0 = *(const bf16x8*)(vbase + a0);
      o0 = __builtin_amdgcn_mfma_f32_32x32x16_bf16(pa[ks16], vf0, o0, 0, 0, 0);
      int row1 = 32 + l31;
      int a1 = (row1 << 6) + ((((ks16 << 1) + hi) ^ ((row1 >> 1) & 3)) << 4);
      bf16x8 vf1 = *(const bf16x8*)(vbase + a1);
      o1 = __builtin_amdgcn_mfma_f32_32x32x16_bf16(pa[ks16], vf1, o1, 0, 0, 0);
    }
    __builtin_amdgcn_s_setprio(0);
  }

  // normalize + store bf16 [b, n, h*64+d]
  const float inv = 1.0f / lsum;
#pragma unroll
  for (int r = 0; r < 16; ++r) {
    int idx = (r & 3) + 8 * (r >> 2) + 4 * hi;
    float ivr = __shfl(inv, idx, 64);
    int qrow = q_lo + idx;
    size_t base = ((size_t)(b * N + qrow)) * 1024 + h * 64;
    ao[base + l31]      = tobf(o0[r] * ivr);
    ao[base + 32 + l31] = tobf(o1[r] * ivr);
  }
}

// ---------------- launch ----------------
extern "C" void kernel_launch(void* const* d_in, const int* in_sizes, int n_in,
                              void* d_out, int out_size, void* d_ws, size_t ws_size,
                              hipStream_t stream) {
  const float* x      = (const float*)d_in[0];
  const float* mask   = (const float*)d_in[1];
  const float* w_qkv  = (const float*)d_in[2];
  const float* q_bias = (const float*)d_in[3];
  const float* k_bias = (const float*)d_in[4];
  const float* v_bias = (const float*)d_in[5];
  const float* w_proj = (const float*)d_in[6];
  const float* b_proj = (const float*)d_in[7];
  float* out = (float*)d_out;

  const int B = 2, N = 2048, C = 1024;
  const int M = B * N;                       // 4096

  // workspace layout (u16 units)
  u16* ws     = (u16*)d_ws;
  u16* xb     = ws;                          // 4096*1024 (x bf16; reused as attn_out)
  u16* wqkvb  = ws + 4194304;                // 3072*1024
  u16* wprojb = ws + 7340032;                // 1024*1024
  u16* qbuf   = ws + 8388608;                // 32*2048*64
  u16* kbuf   = ws + 12582912;
  u16* vtbuf  = ws + 16777216;               // [b,h,d,n]
  unsigned* flag = (unsigned*)(ws + 20971520);
  u16* aob    = xb;                          // reuse: x dead after QKV GEMM

  hipMemsetAsync(flag, 0, 4, stream);
  k_pre<<<2048, 256, 0, stream>>>(x, w_qkv, w_proj, xb, wqkvb, wprojb,
                                  (const u32x4v*)mask, flag);

  k_gemm_nt<0><<<(M / 128) * (3 * C / 128), 256, 0, stream>>>(
      xb, wqkvb, 3 * C, C, 3 * C / 128,
      q_bias, k_bias, v_bias, qbuf, kbuf, vtbuf, nullptr, nullptr);

  k_attn<<<B * 16 * (N / 32), 64, 0, stream>>>(qbuf, kbuf, vtbuf, aob, mask, flag);

  k_gemm_nt<1><<<(M / 128) * (C / 128), 256, 0, stream>>>(
      aob, wprojb, C, C, C / 128,
      nullptr, nullptr, nullptr, nullptr, nullptr, nullptr, out, b_proj);
}

// Round 9
// 143.983 us; speedup vs baseline: 1.1371x; 1.1371x over previous
//
#include <hip/hip_runtime.h>

typedef unsigned short u16;
typedef __bf16   bf16x8 __attribute__((ext_vector_type(8)));
typedef float    f32x4  __attribute__((ext_vector_type(4)));
typedef float    f32x16 __attribute__((ext_vector_type(16)));
typedef unsigned u32x4v __attribute__((ext_vector_type(4)));
typedef u16      u16x8  __attribute__((ext_vector_type(8)));

#define DEV __device__ __forceinline__

DEV u16 tobf(float f) {               // RNE via HW convert
  return __builtin_bit_cast(unsigned short, (__bf16)f);
}

DEV unsigned pack2(float a, float b) { // 2xf32 -> packed 2xbf16
  return (unsigned)tobf(a) | ((unsigned)tobf(b) << 16);
}

DEV f32x4 fzero() { f32x4 z; z[0]=0.f; z[1]=0.f; z[2]=0.f; z[3]=0.f; return z; }

DEV void async_cp16(void* lds, const void* g) {
  __builtin_amdgcn_global_load_lds(
      (const __attribute__((address_space(1))) void*)g,
      (__attribute__((address_space(3))) void*)lds, 16, 0, 0);
}

DEV void cvt8(const float* __restrict__ in, u16* __restrict__ out, int i) {
  const float4* in4 = (const float4*)in;
  float4 a = in4[2*i], b = in4[2*i+1];
  u16x8 r;
  r[0]=tobf(a.x); r[1]=tobf(a.y); r[2]=tobf(a.z); r[3]=tobf(a.w);
  r[4]=tobf(b.x); r[5]=tobf(b.y); r[6]=tobf(b.z); r[7]=tobf(b.w);
  *(u16x8*)(out + 8*(size_t)i) = r;
}

// ---------------- fused pre-pass: f32->bf16 converts + mask-nonzero OR -------
__global__ __launch_bounds__(256)
void k_pre(const float* __restrict__ x, const float* __restrict__ wqkv,
           const float* __restrict__ wproj,
           u16* __restrict__ xb, u16* __restrict__ wqkvb, u16* __restrict__ wprojb,
           const u32x4v* __restrict__ mask, unsigned* __restrict__ flag)
{
  const int tid = blockIdx.x * blockDim.x + threadIdx.x;
  const int stride = gridDim.x * blockDim.x;
  for (int i = tid; i < 524288; i += stride) cvt8(x, xb, i);
  for (int i = tid; i < 393216; i += stride) cvt8(wqkv, wqkvb, i);
  for (int i = tid; i < 131072; i += stride) cvt8(wproj, wprojb, i);
  unsigned o = 0;
  for (int i = tid; i < 2097152; i += stride) {
    u32x4v v = mask[i];
    o |= v[0] | v[1] | v[2] | v[3];
  }
  if (o & 0x7fffffffu) atomicOr(flag, 1u);         // ignore -0.0
}

// ---------------- NT GEMM: C[m,n] = sum_k A[m,k]*B[n,k], bf16 in, f32 acc ----
// 128x128 tile, BK=32, 4 waves. T4: counted vmcnt + RAW barriers so the
// prefetch stays in flight across the barrier (no vmcnt(0) drain per tile).
template<int EPI>
__global__ __launch_bounds__(256)
void k_gemm_nt(const u16* __restrict__ A, const u16* __restrict__ B,
               int N, int K, int nbn,
               const float* __restrict__ bq, const float* __restrict__ bk,
               const float* __restrict__ bv,
               u16* __restrict__ qo, u16* __restrict__ ko, u16* __restrict__ vto,
               float* __restrict__ fo, const float* __restrict__ bp)
{
  __shared__ u16 sA[2][4096];   // [128][32] bf16, chunk-swizzled
  __shared__ u16 sB[2][4096];

  const int tid  = threadIdx.x;
  const int lane = tid & 63;
  const int wave = tid >> 6;
  const int lr = lane & 15, lg = lane >> 4;
  const int wr = wave >> 1, wc = wave & 1;

  const int per = gridDim.x >> 3;
  const int bid = blockIdx.x;
  const int swz = (bid & 7) * per + (bid >> 3);
  const int bm0 = (swz / nbn) << 7;
  const int bn0 = (swz - (swz / nbn) * nbn) << 7;

  const size_t Kb = (size_t)K * 2;

  auto stage = [&](int buf, int kt) {
#pragma unroll
    for (int j = 0; j < 2; ++j) {
      int off = (tid + j * 256) << 4;
      int row = off >> 6;
      int ch  = (off & 63) >> 4;
      int gch = ch ^ (row & 3);
      async_cp16((char*)&sA[buf][0] + off,
                 (const char*)A + (size_t)(bm0 + row) * Kb + (size_t)kt * 64 + gch * 16);
      async_cp16((char*)&sB[buf][0] + off,
                 (const char*)B + (size_t)(bn0 + row) * Kb + (size_t)kt * 64 + gch * 16);
    }
  };

  f32x4 acc[4][4];
#pragma unroll
  for (int i = 0; i < 4; ++i)
#pragma unroll
    for (int j = 0; j < 4; ++j) acc[i][j] = fzero();

  const int nk = K >> 5;
  stage(0, 0);

  for (int kt = 0; kt < nk; ++kt) {
    const int cur = kt & 1;
    if (kt + 1 < nk) {
      stage(cur ^ 1, kt + 1);
      asm volatile("s_waitcnt vmcnt(4)" ::: "memory");  // own prev-tile loads done
    } else {
      asm volatile("s_waitcnt vmcnt(0)" ::: "memory");
    }
    __builtin_amdgcn_s_barrier();            // all waves' prev-tile loads done
    __builtin_amdgcn_sched_barrier(0);       // rule #18: pin ds_reads below

    bf16x8 af[4], bfr[4];
#pragma unroll
    for (int mi = 0; mi < 4; ++mi) {
      int row = (wr << 6) + (mi << 4) + lr;
      int addr = (row << 6) + ((lg ^ (row & 3)) << 4);
      af[mi] = *(const bf16x8*)((const char*)&sA[cur][0] + addr);
    }
#pragma unroll
    for (int ni = 0; ni < 4; ++ni) {
      int row = (wc << 6) + (ni << 4) + lr;
      int addr = (row << 6) + ((lg ^ (row & 3)) << 4);
      bfr[ni] = *(const bf16x8*)((const char*)&sB[cur][0] + addr);
    }
    __builtin_amdgcn_s_setprio(1);
#pragma unroll
    for (int mi = 0; mi < 4; ++mi)
#pragma unroll
      for (int ni = 0; ni < 4; ++ni)
        acc[mi][ni] = __builtin_amdgcn_mfma_f32_16x16x32_bf16(af[mi], bfr[ni], acc[mi][ni], 0, 0, 0);
    __builtin_amdgcn_s_setprio(0);

    __builtin_amdgcn_s_barrier();            // all reads of buf[cur] done
  }

#pragma unroll
  for (int mi = 0; mi < 4; ++mi) {
#pragma unroll
    for (int ni = 0; ni < 4; ++ni) {
      int col = bn0 + (wc << 6) + (ni << 4) + lr;
      if (EPI == 0) {
        int s = col >> 10, hd = col & 1023;
        int h = hd >> 6, d = hd & 63;
        float bias = (s == 0 ? bq[hd] : (s == 1 ? bk[hd] : bv[hd]));
#pragma unroll
        for (int r = 0; r < 4; ++r) {
          int m = bm0 + (wr << 6) + (mi << 4) + (lg << 2) + r;
          int b = m >> 11, n = m & 2047;
          float v = acc[mi][ni][r] + bias;
          if (s == 0) v *= 0.125f;            // fold hd^-0.5 into Q (exact pow2)
          u16 val = tobf(v);
          size_t bh = (size_t)(b * 16 + h);
          if (s == 0)      qo[(bh * 2048 + n) * 64 + d] = val;
          else if (s == 1) ko[(bh * 2048 + n) * 64 + d] = val;
          else             vto[(bh * 64 + d) * 2048 + n] = val;  // V transposed
        }
      } else {
        float bias = bp[col];
#pragma unroll
        for (int r = 0; r < 4; ++r) {
          int m = bm0 + (wr << 6) + (mi << 4) + (lg << 2) + r;
          fo[(size_t)m * N + col] = acc[mi][ni][r] + bias;
        }
      }
    }
  }
}

// ---------------- flash attention, 32x32 MFMA, quad-buffer counted-vmcnt -----
// grid = B*H*(N/128) = 512 blocks, 256 threads (4 waves x 32 q-rows).
// R5-verified math. T4: KV tiles quad-buffered, prefetch depth 2, ONE raw
// s_barrier per tile preceded by counted vmcnt(8) (oldest tile drained, two
// newer tiles stay in flight across the barrier). Quad-buffering makes the
// stage target disjoint from any buffer a lagging wave may still read, so no
// second barrier. Swapped QK^T (mfma(K,Q)); P->A-frag via permlane32_swap;
// Q pre-scaled by 0.125 at QKV epilogue.
__global__ __launch_bounds__(256)
void k_attn(const u16* __restrict__ qb, const u16* __restrict__ kb,
            const u16* __restrict__ vtb, u16* __restrict__ ao,
            const float* __restrict__ mask, const unsigned* __restrict__ flag)
{
  constexpr int N = 2048;
  constexpr int NTT = N / 64;      // 32 KV tiles of 64 keys
  __shared__ u16 sK[4][4096];      // [buf][64 keys][64 d], chunk-swizzled
  __shared__ u16 sV[4][4096];      // [buf][64 d][64 keys] (V^T), chunk-swizzled

  const int tid  = threadIdx.x;
  const int lane = tid & 63;
  const int wave = tid >> 6;
  const int l31  = lane & 31;
  const int hi   = lane >> 5;

  const int bid  = blockIdx.x;
  const int xcd  = bid & 7, slot = bid >> 3;
  const int bh   = xcd + 8 * (slot >> 4);      // 4 bh per XCD -> KV L2-resident
  const int qt   = slot & 15;
  const int b    = bh >> 4, h = bh & 15;

  const u16* Kbh = kb  + (size_t)bh * N * 64;
  const u16* Vbh = vtb + (size_t)bh * 64 * N;
  const int q_lo = qt * 128 + wave * 32;
  const int qg   = q_lo + l31;

  // Q B-frag: lane holds Q[q=l31][d = ks*16 + hi*8 + j]  (pre-scaled by 0.125)
  bf16x8 qf[4];
  {
    const u16* qrow = qb + ((size_t)bh * N + qg) * 64;
#pragma unroll
    for (int ks = 0; ks < 4; ++ks)
      qf[ks] = *(const bf16x8*)(qrow + ks * 16 + hi * 8);
  }

  const unsigned use_mask = *flag;
  const float* maskb = mask + (size_t)b * N * N;

  float m_run = -INFINITY, lsum = 0.f;
  f32x16 o0, o1;
#pragma unroll
  for (int r = 0; r < 16; ++r) { o0[r] = 0.f; o1[r] = 0.f; }

  auto stage = [&](int buf, int kt) {   // 4 VMEM per thread per tile
#pragma unroll
    for (int j = 0; j < 2; ++j) {
      int off = (tid + j * 256) << 4;
      int row = off >> 7;
      int ch  = (off & 127) >> 4;
      int gch = ch ^ (row & 7);
      async_cp16((char*)&sK[buf][0] + off,
                 (const char*)Kbh + (size_t)(kt * 64 + row) * 128 + gch * 16);
      async_cp16((char*)&sV[buf][0] + off,
                 (const char*)Vbh + (size_t)row * (N * 2) + (size_t)kt * 128 + gch * 16);
    }
  };

  stage(0, 0);
  stage(1, 1);

  const float L2E = 1.44269504088896340736f;

  for (int kt = 0; kt < NTT; ++kt) {
    const int cur = kt & 3;
    if (kt + 2 < NTT) stage((kt + 2) & 3, kt + 2);
    // in-flight after optional stage: tiles kt+1, kt+2 (4 VMEM each)
    if (kt + 2 < NTT)      asm volatile("s_waitcnt vmcnt(8)" ::: "memory");
    else if (kt + 1 < NTT) asm volatile("s_waitcnt vmcnt(4)" ::: "memory");
    else                   asm volatile("s_waitcnt vmcnt(0)" ::: "memory");
    __builtin_amdgcn_s_barrier();        // all waves' tile-kt loads complete
    __builtin_amdgcn_sched_barrier(0);   // rule #18: pin ds_reads below

    const char* kbase = (const char*)&sK[cur][0];
    const char* vbase = (const char*)&sV[cur][0];

    // S^T: 2 key-blocks of 32, 4 k-slices of d each
    f32x16 sc0, sc1;
#pragma unroll
    for (int r = 0; r < 16; ++r) { sc0[r] = 0.f; sc1[r] = 0.f; }

    __builtin_amdgcn_s_setprio(1);
#pragma unroll
    for (int ks = 0; ks < 4; ++ks) {
      int row0 = l31;
      int a0 = (row0 << 7) + ((((ks << 1) + hi) ^ (row0 & 7)) << 4);
      bf16x8 kf0 = *(const bf16x8*)(kbase + a0);
      sc0 = __builtin_amdgcn_mfma_f32_32x32x16_bf16(kf0, qf[ks], sc0, 0, 0, 0);
      int row1 = 32 + l31;
      int a1 = (row1 << 7) + ((((ks << 1) + hi) ^ (row1 & 7)) << 4);
      bf16x8 kf1 = *(const bf16x8*)(kbase + a1);
      sc1 = __builtin_amdgcn_mfma_f32_32x32x16_bf16(kf1, qf[ks], sc1, 0, 0, 0);
    }
    __builtin_amdgcn_s_setprio(0);

    if (use_mask) {                      // slow path only if mask != 0
#pragma unroll
      for (int r = 0; r < 16; ++r) {
        int krow = (r & 3) + 8 * (r >> 2) + 4 * hi;
        sc0[r] += maskb[(size_t)qg * N + kt * 64 + krow];
        sc1[r] += maskb[(size_t)qg * N + kt * 64 + 32 + krow];
      }
    }

    // row max over 64 keys: balanced in-lane tree + xor32
    float tmx[8];
#pragma unroll
    for (int r = 0; r < 8; ++r)
      tmx[r] = fmaxf(fmaxf(sc0[r], sc0[r + 8]), fmaxf(sc1[r], sc1[r + 8]));
#pragma unroll
    for (int r = 0; r < 4; ++r) tmx[r] = fmaxf(tmx[r], tmx[r + 4]);
    float pm = fmaxf(fmaxf(tmx[0], tmx[1]), fmaxf(tmx[2], tmx[3]));
    pm = fmaxf(pm, __shfl_xor(pm, 32, 64));

    // defer-max (T13): rescale only when running max grows past THR=8
    if (__any(pm > m_run + 8.f)) {
      const float m_new = fmaxf(m_run, pm);
      const float f = __builtin_amdgcn_exp2f((m_run - m_new) * L2E);
      m_run = m_new;
#pragma unroll
      for (int r = 0; r < 16; ++r) {
        float fr = __shfl(f, (r & 3) + 8 * (r >> 2) + 4 * hi, 64);
        o0[r] *= fr; o1[r] *= fr;
      }
      lsum *= f;
    }

    // p = exp(s - m) in place; 4-way partial sums
    const float mL2 = m_run * L2E;
    float rs0 = 0.f, rs1 = 0.f, rs2 = 0.f, rs3 = 0.f;
#pragma unroll
    for (int r = 0; r < 16; r += 4) {
      sc0[r]   = __builtin_amdgcn_exp2f(__builtin_fmaf(sc0[r],   L2E, -mL2));
      sc0[r+1] = __builtin_amdgcn_exp2f(__builtin_fmaf(sc0[r+1], L2E, -mL2));
      sc0[r+2] = __builtin_amdgcn_exp2f(__builtin_fmaf(sc0[r+2], L2E, -mL2));
      sc0[r+3] = __builtin_amdgcn_exp2f(__builtin_fmaf(sc0[r+3], L2E, -mL2));
      sc1[r]   = __builtin_amdgcn_exp2f(__builtin_fmaf(sc1[r],   L2E, -mL2));
      sc1[r+1] = __builtin_amdgcn_exp2f(__builtin_fmaf(sc1[r+1], L2E, -mL2));
      sc1[r+2] = __builtin_amdgcn_exp2f(__builtin_fmaf(sc1[r+2], L2E, -mL2));
      sc1[r+3] = __builtin_amdgcn_exp2f(__builtin_fmaf(sc1[r+3], L2E, -mL2));
      rs0 += sc0[r]   + sc1[r];
      rs1 += sc0[r+1] + sc1[r+1];
      rs2 += sc0[r+2] + sc1[r+2];
      rs3 += sc0[r+3] + sc1[r+3];
    }
    float rs = (rs0 + rs1) + (rs2 + rs3);
    rs += __shfl_xor(rs, 32, 64);
    lsum += rs;

    // pack pairs
    unsigned P32_0[8], P32_1[8];
#pragma unroll
    for (int tt = 0; tt < 8; ++tt) {
      P32_0[tt] = pack2(sc0[2 * tt], sc0[2 * tt + 1]);
      P32_1[tt] = pack2(sc1[2 * tt], sc1[2 * tt + 1]);
    }

    // redistribute to PV A-frag via permlane32_swap
    bf16x8 pa[4];
#pragma unroll
    for (int ks16 = 0; ks16 < 4; ++ks16) {
      const int b4 = (ks16 & 1) << 2;
      unsigned c0, c1, c2, c3;
      if (ks16 < 2) { c0 = P32_0[b4]; c2 = P32_0[b4+2]; c1 = P32_0[b4+1]; c3 = P32_0[b4+3]; }
      else          { c0 = P32_1[b4]; c2 = P32_1[b4+2]; c1 = P32_1[b4+1]; c3 = P32_1[b4+3]; }
      asm volatile("v_permlane32_swap_b32 %0, %1" : "+v"(c0), "+v"(c2));
      asm volatile("v_permlane32_swap_b32 %0, %1" : "+v"(c1), "+v"(c3));
      u32x4v w; w[0] = c0; w[1] = c1; w[2] = c2; w[3] = c3;
      pa[ks16] = __builtin_bit_cast(bf16x8, w);
    }

    // O += P * V
    __builtin_amdgcn_s_setprio(1);
#pragma unroll
    for (int ks16 = 0; ks16 < 4; ++ks16) {
      int row0 = l31;
      int a0 = (row0 << 7) + ((((ks16 << 1) + hi) ^ (row0 & 7)) << 4);
      bf16x8 vf0 = *(const bf16x8*)(vbase + a0);
      o0 = __builtin_amdgcn_mfma_f32_32x32x16_bf16(pa[ks16], vf0, o0, 0, 0, 0);
      int row1 = 32 + l31;
      int a1 = (row1 << 7) + ((((ks16 << 1) + hi) ^ (row1 & 7)) << 4);
      bf16x8 vf1 = *(const bf16x8*)(vbase + a1);
      o1 = __builtin_amdgcn_mfma_f32_32x32x16_bf16(pa[ks16], vf1, o1, 0, 0, 0);
    }
    __builtin_amdgcn_s_setprio(0);
    // no trailing barrier: quad-buffer guarantees the next stage target is
    // disjoint from any buffer a lagging wave may still be reading.
  }

  // normalize + store bf16 [b, n, h*64+d]
  const float inv = 1.0f / lsum;
#pragma unroll
  for (int r = 0; r < 16; ++r) {
    int idx = (r & 3) + 8 * (r >> 2) + 4 * hi;
    float ivr = __shfl(inv, idx, 64);
    int qrow = q_lo + idx;
    size_t base = ((size_t)(b * N + qrow)) * 1024 + h * 64;
    ao[base + l31]      = tobf(o0[r] * ivr);
    ao[base + 32 + l31] = tobf(o1[r] * ivr);
  }
}

// ---------------- launch ----------------
extern "C" void kernel_launch(void* const* d_in, const int* in_sizes, int n_in,
                              void* d_out, int out_size, void* d_ws, size_t ws_size,
                              hipStream_t stream) {
  const float* x      = (const float*)d_in[0];
  const float* mask   = (const float*)d_in[1];
  const float* w_qkv  = (const float*)d_in[2];
  const float* q_bias = (const float*)d_in[3];
  const float* k_bias = (const float*)d_in[4];
  const float* v_bias = (const float*)d_in[5];
  const float* w_proj = (const float*)d_in[6];
  const float* b_proj = (const float*)d_in[7];
  float* out = (float*)d_out;

  const int B = 2, N = 2048, C = 1024;
  const int M = B * N;                       // 4096

  // workspace layout (u16 units)
  u16* ws     = (u16*)d_ws;
  u16* xb     = ws;                          // 4096*1024 (x bf16; reused as attn_out)
  u16* wqkvb  = ws + 4194304;                // 3072*1024
  u16* wprojb = ws + 7340032;                // 1024*1024
  u16* qbuf   = ws + 8388608;                // 32*2048*64
  u16* kbuf   = ws + 12582912;
  u16* vtbuf  = ws + 16777216;               // [b,h,d,n]
  unsigned* flag = (unsigned*)(ws + 20971520);
  u16* aob    = xb;                          // reuse: x dead after QKV GEMM

  hipMemsetAsync(flag, 0, 4, stream);
  k_pre<<<2048, 256, 0, stream>>>(x, w_qkv, w_proj, xb, wqkvb, wprojb,
                                  (const u32x4v*)mask, flag);

  k_gemm_nt<0><<<(M / 128) * (3 * C / 128), 256, 0, stream>>>(
      xb, wqkvb, 3 * C, C, 3 * C / 128,
      q_bias, k_bias, v_bias, qbuf, kbuf, vtbuf, nullptr, nullptr);

  k_attn<<<B * 16 * (N / 128), 256, 0, stream>>>(qbuf, kbuf, vtbuf, aob, mask, flag);

  k_gemm_nt<1><<<(M / 128) * (C / 128), 256, 0, stream>>>(
      aob, wprojb, C, C, C / 128,
      nullptr, nullptr, nullptr, nullptr, nullptr, nullptr, out, b_proj);
}